// Round 1
// baseline (2761.851 us; speedup 1.0000x reference)
//
#include <hip/hip_runtime.h>
#include <math.h>

#define B_ 256
#define T_ 512
#define F_ 378
#define C_ 128
#define H_ 64

// ---------------- Conv1d(378->128, k=3, pad=1) + ReLU ----------------
// Implicit GEMM: y[b,t,c] = relu(sum_{f,k} x[b,t+k-1,f] * w[c,f,k] + bias[c])
// Block: 32 consecutive t for one b, 256 threads (c = tid&127, tg = tid>>7).
// x tile staged in LDS (rows t0-1..t0+32, f padded to 384); w staged in
// f-chunks of 16 (rows padded to 49 floats -> bank-conflict-free).
#define TT 32
#define FPAD 384

__global__ __launch_bounds__(256) void conv_relu_kernel(
    const float* __restrict__ x, const float* __restrict__ w,
    const float* __restrict__ bias, float* __restrict__ y) {
  __shared__ __align__(16) float xs[34 * FPAD];
  __shared__ float ws[128 * 49];
  const int blk = blockIdx.x;
  const int b = blk / (T_ / TT);
  const int t0 = (blk % (T_ / TT)) * TT;
  const int tid = threadIdx.x;

  // stage x rows t0-1 .. t0+32 (zero-padded in t and f)
  for (int i = tid; i < 34 * FPAD; i += 256) {
    int r = i / FPAD, f = i - r * FPAD;
    int t = t0 - 1 + r;
    float v = 0.f;
    if (f < F_ && t >= 0 && t < T_) v = x[((long)b * T_ + t) * F_ + f];
    xs[r * FPAD + f] = v;
  }

  const int c = tid & 127;
  const int tg = tid >> 7;
  float acc[16];
#pragma unroll
  for (int j = 0; j < 16; ++j) acc[j] = 0.f;

  for (int f0 = 0; f0 < FPAD; f0 += 16) {
    __syncthreads();  // protect ws from previous chunk's readers
    // stage w chunk: ws[c][f_local*3+k], rows padded to 49
    for (int i = tid; i < 128 * 48; i += 256) {
      int cc = i / 48, m = i - cc * 48;
      int fl = m / 3, k = m - fl * 3;
      int fg = f0 + fl;
      float v = 0.f;
      if (fg < F_) v = w[cc * (F_ * 3) + fg * 3 + k];
      ws[cc * 49 + m] = v;
    }
    __syncthreads();
#pragma unroll
    for (int fg = 0; fg < 4; ++fg) {
      float4 xv[18];
#pragma unroll
      for (int r = 0; r < 18; ++r)
        xv[r] = *(const float4*)&xs[(tg * 16 + r) * FPAD + f0 + fg * 4];
      float wv[12];
#pragma unroll
      for (int m = 0; m < 12; ++m) wv[m] = ws[c * 49 + fg * 12 + m];
#pragma unroll
      for (int j = 0; j < 16; ++j) {
#pragma unroll
        for (int k = 0; k < 3; ++k) {
          float4 xr = xv[j + k];  // static index after unroll
          acc[j] += xr.x * wv[0 * 3 + k] + xr.y * wv[1 * 3 + k] +
                    xr.z * wv[2 * 3 + k] + xr.w * wv[3 * 3 + k];
        }
      }
    }
  }

  const float bc = bias[c];
#pragma unroll
  for (int j = 0; j < 16; ++j) {
    int t = t0 + tg * 16 + j;
    float v = acc[j] + bc;
    y[((long)b * T_ + t) * C_ + c] = v > 0.f ? v : 0.f;
  }
}

// ---------------- BiLSTM, one block per (batch, direction) ----------------
// 256 threads; thread g owns gate g (pytorch order i,f,g,o chunks of 64).
// w_ih row (128 f) + w_hh row (64 f) in registers; y row + h + gates via LDS.
// Input projection computed on the fly (saves 268 MB of xg scratch).
__device__ __forceinline__ float sigm(float v) {
  return 1.f / (1.f + __expf(-v));
}
__device__ __forceinline__ float tanh_fast(float v) {
  return 2.f / (1.f + __expf(-2.f * v)) - 1.f;
}

__global__ __launch_bounds__(256) void lstm_kernel(
    const float* __restrict__ y, const float* __restrict__ w_ih_f,
    const float* __restrict__ w_hh_f, const float* __restrict__ b_f,
    const float* __restrict__ w_ih_b, const float* __restrict__ w_hh_b,
    const float* __restrict__ b_b, float* __restrict__ out) {
  const int dir = blockIdx.x & 1;
  const int b = blockIdx.x >> 1;
  const int g = threadIdx.x;
  const float* wih = dir ? w_ih_b : w_ih_f;
  const float* whh = dir ? w_hh_b : w_hh_f;
  const float* bb = dir ? b_b : b_f;

  float wi[128], wh[64];
#pragma unroll
  for (int j = 0; j < 128; ++j) wi[j] = wih[g * 128 + j];
#pragma unroll
  for (int j = 0; j < 64; ++j) wh[j] = whh[g * 64 + j];
  const float bg = bb[g];

  __shared__ __align__(16) float yrow[128];
  __shared__ __align__(16) float hs[64];
  __shared__ float gates[256];
  float cst = 0.f;
  if (g < 64) hs[g] = 0.f;

  for (int s = 0; s < T_; ++s) {
    const int t = dir ? (T_ - 1 - s) : s;
    if (g < 128) yrow[g] = y[((long)b * T_ + t) * C_ + g];
    __syncthreads();  // yrow ready, hs from prev step ready
    float acc = bg;
#pragma unroll
    for (int j = 0; j < 128; ++j) acc += yrow[j] * wi[j];
#pragma unroll
    for (int j = 0; j < 64; ++j) acc += hs[j] * wh[j];
    gates[g] = acc;
    __syncthreads();  // gates ready
    if (g < 64) {
      float gi = gates[g], gf = gates[64 + g];
      float gc = gates[128 + g], go = gates[192 + g];
      cst = sigm(gf) * cst + sigm(gi) * tanh_fast(gc);
      float h = sigm(go) * tanh_fast(cst);
      hs[g] = h;
      out[((long)b * T_ + t) * (2 * H_) + dir * H_ + g] = h;
    }
    __syncthreads();  // hs updated before next iter overwrites yrow/gates
  }
}

// ---------------- Attention pool + LayerNorm + FC ----------------
__global__ __launch_bounds__(256) void head_kernel(
    const float* __restrict__ hio, const float* __restrict__ attn_w,
    const float* __restrict__ attn_b, const float* __restrict__ ln_g,
    const float* __restrict__ ln_b, const float* __restrict__ fc_w,
    const float* __restrict__ fc_b, float* __restrict__ res) {
  const int b = blockIdx.x;
  const int tid = threadIdx.x;
  __shared__ __align__(16) float aw[128];
  __shared__ float l[T_];
  __shared__ float red[16];
  __shared__ float pp[2][128];
  __shared__ float normed[128];
  if (tid < 128) aw[tid] = attn_w[tid];
  __syncthreads();
  const float ab = attn_b[0];

  // logits over T
  for (int t = tid; t < T_; t += 256) {
    const float* row = hio + ((long)b * T_ + t) * 128;
    float a = ab;
#pragma unroll
    for (int d = 0; d < 128; d += 4) {
      float4 r4 = *(const float4*)&row[d];
      float4 w4 = *(const float4*)&aw[d];
      a += r4.x * w4.x + r4.y * w4.y + r4.z * w4.z + r4.w * w4.w;
    }
    l[t] = a;
  }
  __syncthreads();

  // softmax over 512 (each thread holds 2)
  float v0 = l[tid], v1 = l[tid + 256];
  float m = fmaxf(v0, v1);
#pragma unroll
  for (int off = 32; off >= 1; off >>= 1) m = fmaxf(m, __shfl_xor(m, off));
  if ((tid & 63) == 0) red[tid >> 6] = m;
  __syncthreads();
  m = fmaxf(fmaxf(red[0], red[1]), fmaxf(red[2], red[3]));
  float e0 = __expf(v0 - m), e1 = __expf(v1 - m);
  float ssum = e0 + e1;
#pragma unroll
  for (int off = 32; off >= 1; off >>= 1) ssum += __shfl_xor(ssum, off);
  if ((tid & 63) == 0) red[4 + (tid >> 6)] = ssum;
  __syncthreads();
  float inv = 1.f / (red[4] + red[5] + red[6] + red[7]);
  l[tid] = e0 * inv;
  l[tid + 256] = e1 * inv;
  __syncthreads();

  // pooled[d] = sum_t w_t * hio[b,t,d]; split T across 2 halves of the block
  const int d = tid & 127, half = tid >> 7;
  float p = 0.f;
  for (int t = half * 256; t < half * 256 + 256; ++t)
    p += l[t] * hio[((long)b * T_ + t) * 128 + d];
  pp[half][d] = p;
  __syncthreads();

  // LayerNorm over 128 dims (threads 0..127)
  if (tid < 128) {
    float pv = pp[0][tid] + pp[1][tid];
    float s1 = pv, s2 = pv * pv;
#pragma unroll
    for (int off = 32; off >= 1; off >>= 1) {
      s1 += __shfl_xor(s1, off);
      s2 += __shfl_xor(s2, off);
    }
    if ((tid & 63) == 0) {
      red[8 + (tid >> 6) * 2] = s1;
      red[9 + (tid >> 6) * 2] = s2;
    }
  }
  __syncthreads();
  if (tid < 128) {
    float s1 = red[8] + red[10], s2 = red[9] + red[11];
    float mu = s1 * (1.f / 128.f);
    float var = s2 * (1.f / 128.f) - mu * mu;
    float rinv = rsqrtf(var + 1e-5f);
    float pv = pp[0][tid] + pp[1][tid];
    normed[tid] = (pv - mu) * rinv * ln_g[tid] + ln_b[tid];
  }
  __syncthreads();

  // FC 128 -> 2
  if (tid < 2) {
    float a = fc_b[tid];
    for (int d2 = 0; d2 < 128; ++d2) a += normed[d2] * fc_w[tid * 128 + d2];
    res[b * 2 + tid] = a;
  }
}

extern "C" void kernel_launch(void* const* d_in, const int* in_sizes, int n_in,
                              void* d_out, int out_size, void* d_ws,
                              size_t ws_size, hipStream_t stream) {
  const float* x = (const float*)d_in[0];
  const float* conv_w = (const float*)d_in[1];
  const float* conv_b = (const float*)d_in[2];
  const float* w_ih_f = (const float*)d_in[3];
  const float* w_hh_f = (const float*)d_in[4];
  const float* b_f = (const float*)d_in[5];
  const float* w_ih_b = (const float*)d_in[6];
  const float* w_hh_b = (const float*)d_in[7];
  const float* b_b = (const float*)d_in[8];
  const float* attn_w = (const float*)d_in[9];
  const float* attn_b = (const float*)d_in[10];
  const float* ln_g = (const float*)d_in[11];
  const float* ln_b = (const float*)d_in[12];
  const float* fc_w = (const float*)d_in[13];
  const float* fc_b = (const float*)d_in[14];
  float* res = (float*)d_out;

  float* y = (float*)d_ws;                    // [B,T,128] = 67.1 MB
  float* hout = y + (size_t)B_ * T_ * C_;     // [B,T,128] = 67.1 MB

  conv_relu_kernel<<<B_ * (T_ / TT), 256, 0, stream>>>(x, conv_w, conv_b, y);
  lstm_kernel<<<B_ * 2, 256, 0, stream>>>(y, w_ih_f, w_hh_f, b_f, w_ih_b,
                                          w_hh_b, b_b, hout);
  head_kernel<<<B_, 256, 0, stream>>>(hout, attn_w, attn_b, ln_g, ln_b, fc_w,
                                      fc_b, res);
}

// Round 2
// 1240.034 us; speedup vs baseline: 2.2272x; 2.2272x over previous
//
#include <hip/hip_runtime.h>
#include <math.h>

typedef unsigned int uint;
typedef unsigned short ushort;

#define B_ 256
#define T_ 512
#define F_ 378
#define C_ 128
#define H_ 64
#define KPAD 1152   // 3 * 384
#define NKS 18      // 1152 / 64

using f32x4 = __attribute__((ext_vector_type(4))) float;
using bf16x8 = __attribute__((ext_vector_type(8))) short;

__device__ __forceinline__ ushort f2bf(float f) {
  union { float f; uint u; } c; c.f = f;
  uint r = (c.u + 0x7fffu + ((c.u >> 16) & 1u)) >> 16;
  return (ushort)r;
}
__device__ __forceinline__ float bf2f(ushort u) {
  union { uint u; float f; } c; c.u = ((uint)u) << 16;
  return c.f;
}
__device__ __forceinline__ uint packbf2(float a, float b) {
  return (uint)f2bf(a) | (((uint)f2bf(b)) << 16);
}

// ---------------- pack w -> wbT[c][kk], kk = k*384 + f, bf16, zero-padded ---
__global__ __launch_bounds__(256) void pack_w_kernel(
    const float* __restrict__ w, ushort* __restrict__ wbT) {
  int i = blockIdx.x * 256 + threadIdx.x;
  if (i >= C_ * KPAD) return;
  int c = i / KPAD, kk = i - c * KPAD;
  int k = kk / 384, f = kk - k * 384;
  float v = (f < F_) ? w[c * (F_ * 3) + f * 3 + k] : 0.f;
  wbT[i] = f2bf(v);
}

// ---------------- Conv1d as implicit GEMM, bf16 MFMA --------------------
// M = B*T (tiles of 128 t within one b), N = C = 128, K = 1152.
// A[m=(b,t)][kk=k*384+f] = x[b][t+k-1][f]  (reg-staged fp32 -> bf16)
// B[kk][c] read as wbT[c][kk] rows (B-frag wants col-major-in-K rows).
// LDS tiles As/Bs [128 rows][64 kk] bf16 with XOR swizzle (row&7)<<4.
__global__ __launch_bounds__(256) void conv_gemm_kernel(
    const float* __restrict__ x, const ushort* __restrict__ wbT,
    const float* __restrict__ bias, ushort* __restrict__ y) {
  __shared__ __align__(16) ushort As[8192];
  __shared__ __align__(16) ushort Bs[8192];
  const int tid = threadIdx.x;
  const int lane = tid & 63;
  const int wr = (tid >> 7) & 1;  // wave row quadrant
  const int wc = (tid >> 6) & 1;  // wave col quadrant
  const int b = blockIdx.x >> 2;
  const int t0 = (blockIdx.x & 3) << 7;

  f32x4 acc[4][4];
#pragma unroll
  for (int m = 0; m < 4; ++m)
#pragma unroll
    for (int n = 0; n < 4; ++n) acc[m][n] = (f32x4)(0.f);

  const int ar = tid >> 1;        // staging row 0..127 (A-row and B-row=c)
  const int ae = (tid & 1) << 5;  // elem offset within 64-wide K slice
  const int swz = (ar & 7) << 4;

  float2 av[16];
  uint4 bv[4];

  // ---- load tile ks=0 into regs ----
  int k = 0, f0 = 0;
  {
    const int trow = t0 + ar + k - 1;
    const bool rowok = (trow >= 0) && (trow < T_);
    const float* srcrow = x + ((long)b * T_ + (rowok ? trow : 0)) * F_;
#pragma unroll
    for (int j = 0; j < 16; ++j) {
      const int f = f0 + ae + 2 * j;
      float2 v = {0.f, 0.f};
      if (rowok && f < F_) v = *(const float2*)(srcrow + f);
      av[j] = v;
    }
    const ushort* srcb = wbT + ar * KPAD + 0 * 64 + ae;
#pragma unroll
    for (int j = 0; j < 4; ++j) bv[j] = *(const uint4*)(srcb + 8 * j);
  }

  for (int ks = 0; ks < NKS; ++ks) {
    __syncthreads();  // all waves done reading LDS from previous step
    // ---- store regs -> LDS (swizzled) ----
    {
      char* arow = (char*)As + ar * 128;
      char* brow = (char*)Bs + ar * 128;
#pragma unroll
      for (int j16 = 0; j16 < 4; ++j16) {
        uint4 p;
        p.x = packbf2(av[4 * j16 + 0].x, av[4 * j16 + 0].y);
        p.y = packbf2(av[4 * j16 + 1].x, av[4 * j16 + 1].y);
        p.z = packbf2(av[4 * j16 + 2].x, av[4 * j16 + 2].y);
        p.w = packbf2(av[4 * j16 + 3].x, av[4 * j16 + 3].y);
        const int inner = ((ae << 1) + (j16 << 4)) ^ swz;
        *(uint4*)(arow + inner) = p;
        *(uint4*)(brow + inner) = bv[j16];
      }
    }
    __syncthreads();  // tiles visible

    // ---- prefetch next tile into regs (overlaps with MFMA below) ----
    if (ks + 1 < NKS) {
      f0 += 64;
      if (f0 == 384) { f0 = 0; ++k; }
      const int trow = t0 + ar + k - 1;
      const bool rowok = (trow >= 0) && (trow < T_);
      const float* srcrow = x + ((long)b * T_ + (rowok ? trow : 0)) * F_;
#pragma unroll
      for (int j = 0; j < 16; ++j) {
        const int f = f0 + ae + 2 * j;
        float2 v = {0.f, 0.f};
        if (rowok && f < F_) v = *(const float2*)(srcrow + f);
        av[j] = v;
      }
      const ushort* srcb = wbT + ar * KPAD + (ks + 1) * 64 + ae;
#pragma unroll
      for (int j = 0; j < 4; ++j) bv[j] = *(const uint4*)(srcb + 8 * j);
    }

    // ---- MFMA over 2 k-slices of 32 ----
#pragma unroll
    for (int s = 0; s < 2; ++s) {
      bf16x8 af[4], bf[4];
      const int ksub = s * 64 + ((lane >> 4) << 4);
      const int rsw = (lane & 7) << 4;  // row&7 swizzle (row%8 == lane%8 here)
#pragma unroll
      for (int m = 0; m < 4; ++m) {
        const int r = wr * 64 + m * 16 + (lane & 15);
        af[m] = *(const bf16x8*)((const char*)As + r * 128 + (ksub ^ rsw));
      }
#pragma unroll
      for (int n = 0; n < 4; ++n) {
        const int r = wc * 64 + n * 16 + (lane & 15);
        bf[n] = *(const bf16x8*)((const char*)Bs + r * 128 + (ksub ^ rsw));
      }
#pragma unroll
      for (int m = 0; m < 4; ++m)
#pragma unroll
        for (int n = 0; n < 4; ++n)
          acc[m][n] =
              __builtin_amdgcn_mfma_f32_16x16x32_bf16(af[m], bf[n], acc[m][n], 0, 0, 0);
    }
  }

  // ---- epilogue: bias + ReLU, store bf16 y[b][t][c] ----
  float bc[4];
#pragma unroll
  for (int n = 0; n < 4; ++n) bc[n] = bias[wc * 64 + n * 16 + (lane & 15)];
#pragma unroll
  for (int m = 0; m < 4; ++m) {
    const int trowbase = t0 + wr * 64 + m * 16 + ((lane >> 4) << 2);
#pragma unroll
    for (int n = 0; n < 4; ++n) {
      const int c = wc * 64 + n * 16 + (lane & 15);
#pragma unroll
      for (int r = 0; r < 4; ++r) {
        float v = acc[m][n][r] + bc[n];
        v = v > 0.f ? v : 0.f;
        y[((long)b * T_ + trowbase + r) * C_ + c] = f2bf(v);
      }
    }
  }
}

// ---------------- BiLSTM, one block per (batch, direction) ----------------
__device__ __forceinline__ float sigm(float v) {
  return 1.f / (1.f + __expf(-v));
}
__device__ __forceinline__ float tanh_fast(float v) {
  return 2.f / (1.f + __expf(-2.f * v)) - 1.f;
}

__global__ __launch_bounds__(256) void lstm_kernel(
    const ushort* __restrict__ y, const float* __restrict__ w_ih_f,
    const float* __restrict__ w_hh_f, const float* __restrict__ b_f,
    const float* __restrict__ w_ih_b, const float* __restrict__ w_hh_b,
    const float* __restrict__ b_b, float* __restrict__ out) {
  const int dir = blockIdx.x & 1;
  const int b = blockIdx.x >> 1;
  const int g = threadIdx.x;
  const float* wih = dir ? w_ih_b : w_ih_f;
  const float* whh = dir ? w_hh_b : w_hh_f;
  const float* bb = dir ? b_b : b_f;

  float wi[128], wh[64];
#pragma unroll
  for (int j = 0; j < 128; ++j) wi[j] = wih[g * 128 + j];
#pragma unroll
  for (int j = 0; j < 64; ++j) wh[j] = whh[g * 64 + j];
  const float bg = bb[g];

  __shared__ __align__(16) float yrow[128];
  __shared__ __align__(16) float hs[64];
  __shared__ float gates[256];
  float cst = 0.f;
  if (g < 64) hs[g] = 0.f;

  for (int s = 0; s < T_; ++s) {
    const int t = dir ? (T_ - 1 - s) : s;
    if (g < 128) yrow[g] = bf2f(y[((long)b * T_ + t) * C_ + g]);
    __syncthreads();  // yrow ready, hs from prev step ready
    float acc = bg;
#pragma unroll
    for (int j = 0; j < 128; ++j) acc += yrow[j] * wi[j];
#pragma unroll
    for (int j = 0; j < 64; ++j) acc += hs[j] * wh[j];
    gates[g] = acc;
    __syncthreads();  // gates ready
    if (g < 64) {
      float gi = gates[g], gf = gates[64 + g];
      float gc = gates[128 + g], go = gates[192 + g];
      cst = sigm(gf) * cst + sigm(gi) * tanh_fast(gc);
      float h = sigm(go) * tanh_fast(cst);
      hs[g] = h;
      out[((long)b * T_ + t) * (2 * H_) + dir * H_ + g] = h;
    }
    __syncthreads();  // hs updated before next iter overwrites yrow/gates
  }
}

// ---------------- Attention pool + LayerNorm + FC ----------------
__global__ __launch_bounds__(256) void head_kernel(
    const float* __restrict__ hio, const float* __restrict__ attn_w,
    const float* __restrict__ attn_b, const float* __restrict__ ln_g,
    const float* __restrict__ ln_b, const float* __restrict__ fc_w,
    const float* __restrict__ fc_b, float* __restrict__ res) {
  const int b = blockIdx.x;
  const int tid = threadIdx.x;
  __shared__ __align__(16) float aw[128];
  __shared__ float l[T_];
  __shared__ float red[16];
  __shared__ float pp[2][128];
  __shared__ float normed[128];
  if (tid < 128) aw[tid] = attn_w[tid];
  __syncthreads();
  const float ab = attn_b[0];

  for (int t = tid; t < T_; t += 256) {
    const float* row = hio + ((long)b * T_ + t) * 128;
    float a = ab;
#pragma unroll
    for (int d = 0; d < 128; d += 4) {
      float4 r4 = *(const float4*)&row[d];
      float4 w4 = *(const float4*)&aw[d];
      a += r4.x * w4.x + r4.y * w4.y + r4.z * w4.z + r4.w * w4.w;
    }
    l[t] = a;
  }
  __syncthreads();

  float v0 = l[tid], v1 = l[tid + 256];
  float m = fmaxf(v0, v1);
#pragma unroll
  for (int off = 32; off >= 1; off >>= 1) m = fmaxf(m, __shfl_xor(m, off));
  if ((tid & 63) == 0) red[tid >> 6] = m;
  __syncthreads();
  m = fmaxf(fmaxf(red[0], red[1]), fmaxf(red[2], red[3]));
  float e0 = __expf(v0 - m), e1 = __expf(v1 - m);
  float ssum = e0 + e1;
#pragma unroll
  for (int off = 32; off >= 1; off >>= 1) ssum += __shfl_xor(ssum, off);
  if ((tid & 63) == 0) red[4 + (tid >> 6)] = ssum;
  __syncthreads();
  float inv = 1.f / (red[4] + red[5] + red[6] + red[7]);
  l[tid] = e0 * inv;
  l[tid + 256] = e1 * inv;
  __syncthreads();

  const int d = tid & 127, half = tid >> 7;
  float p = 0.f;
  for (int t = half * 256; t < half * 256 + 256; ++t)
    p += l[t] * hio[((long)b * T_ + t) * 128 + d];
  pp[half][d] = p;
  __syncthreads();

  if (tid < 128) {
    float pv = pp[0][tid] + pp[1][tid];
    float s1 = pv, s2 = pv * pv;
#pragma unroll
    for (int off = 32; off >= 1; off >>= 1) {
      s1 += __shfl_xor(s1, off);
      s2 += __shfl_xor(s2, off);
    }
    if ((tid & 63) == 0) {
      red[8 + (tid >> 6) * 2] = s1;
      red[9 + (tid >> 6) * 2] = s2;
    }
  }
  __syncthreads();
  if (tid < 128) {
    float s1 = red[8] + red[10], s2 = red[9] + red[11];
    float mu = s1 * (1.f / 128.f);
    float var = s2 * (1.f / 128.f) - mu * mu;
    float rinv = rsqrtf(var + 1e-5f);
    float pv = pp[0][tid] + pp[1][tid];
    normed[tid] = (pv - mu) * rinv * ln_g[tid] + ln_b[tid];
  }
  __syncthreads();

  if (tid < 2) {
    float a = fc_b[tid];
    for (int d2 = 0; d2 < 128; ++d2) a += normed[d2] * fc_w[tid * 128 + d2];
    res[b * 2 + tid] = a;
  }
}

extern "C" void kernel_launch(void* const* d_in, const int* in_sizes, int n_in,
                              void* d_out, int out_size, void* d_ws,
                              size_t ws_size, hipStream_t stream) {
  const float* x = (const float*)d_in[0];
  const float* conv_w = (const float*)d_in[1];
  const float* conv_b = (const float*)d_in[2];
  const float* w_ih_f = (const float*)d_in[3];
  const float* w_hh_f = (const float*)d_in[4];
  const float* b_f = (const float*)d_in[5];
  const float* w_ih_b = (const float*)d_in[6];
  const float* w_hh_b = (const float*)d_in[7];
  const float* b_b = (const float*)d_in[8];
  const float* attn_w = (const float*)d_in[9];
  const float* attn_b = (const float*)d_in[10];
  const float* ln_g = (const float*)d_in[11];
  const float* ln_b = (const float*)d_in[12];
  const float* fc_w = (const float*)d_in[13];
  const float* fc_b = (const float*)d_in[14];
  float* res = (float*)d_out;

  // ws layout (peak ~97 MiB):
  ushort* wbT = (ushort*)d_ws;                              // 294,912 B
  ushort* y = (ushort*)((char*)d_ws + 524288);              // 33,554,432 B
  float* hout = (float*)((char*)d_ws + 524288 + 33554432);  // 67,108,864 B

  pack_w_kernel<<<(C_ * KPAD + 255) / 256, 256, 0, stream>>>(conv_w, wbT);
  conv_gemm_kernel<<<B_ * (T_ / 128), 256, 0, stream>>>(x, wbT, conv_b, y);
  lstm_kernel<<<B_ * 2, 256, 0, stream>>>(y, w_ih_f, w_hh_f, b_f, w_ih_b,
                                          w_hh_b, b_b, hout);
  head_kernel<<<B_, 256, 0, stream>>>(hout, attn_w, attn_b, ln_g, ln_b, fc_w,
                                      fc_b, res);
}

// Round 3
// 899.800 us; speedup vs baseline: 3.0694x; 1.3781x over previous
//
#include <hip/hip_runtime.h>
#include <math.h>

typedef unsigned int uint;
typedef unsigned short ushort;

#define B_ 256
#define T_ 512
#define F_ 378
#define C_ 128
#define H_ 64
#define KPAD 1152   // 3 * 384
#define NKS 18      // 1152 / 64

using f32x4 = __attribute__((ext_vector_type(4))) float;
using bf16x8 = __attribute__((ext_vector_type(8))) short;

__device__ __forceinline__ ushort f2bf(float f) {
  union { float f; uint u; } c; c.f = f;
  uint r = (c.u + 0x7fffu + ((c.u >> 16) & 1u)) >> 16;
  return (ushort)r;
}
__device__ __forceinline__ float bf2f(ushort u) {
  union { uint u; float f; } c; c.u = ((uint)u) << 16;
  return c.f;
}
__device__ __forceinline__ uint packbf2(float a, float b) {
  return (uint)f2bf(a) | (((uint)f2bf(b)) << 16);
}

// ---------------- pack w -> wbT[c][kk], kk = k*384 + f, bf16, zero-padded ---
__global__ __launch_bounds__(256) void pack_w_kernel(
    const float* __restrict__ w, ushort* __restrict__ wbT) {
  int i = blockIdx.x * 256 + threadIdx.x;
  if (i >= C_ * KPAD) return;
  int c = i / KPAD, kk = i - c * KPAD;
  int k = kk / 384, f = kk - k * 384;
  float v = (f < F_) ? w[c * (F_ * 3) + f * 3 + k] : 0.f;
  wbT[i] = f2bf(v);
}

// ---------------- pack w_ih (both dirs) -> wbI[dir][g][c] bf16 -------------
__global__ __launch_bounds__(256) void pack_wi_kernel(
    const float* __restrict__ wf, const float* __restrict__ wb,
    ushort* __restrict__ wbI) {
  int i = blockIdx.x * 256 + threadIdx.x;  // 2*256*128 = 65536
  int dir = i >> 15, rem = i & 32767;
  const float* src = dir ? wb : wf;
  wbI[i] = f2bf(src[rem]);
}

// ---------------- Conv1d as implicit GEMM, bf16 MFMA --------------------
__global__ __launch_bounds__(256) void conv_gemm_kernel(
    const float* __restrict__ x, const ushort* __restrict__ wbT,
    const float* __restrict__ bias, ushort* __restrict__ y) {
  __shared__ __align__(16) ushort As[8192];
  __shared__ __align__(16) ushort Bs[8192];
  const int tid = threadIdx.x;
  const int lane = tid & 63;
  const int wr = (tid >> 7) & 1;
  const int wc = (tid >> 6) & 1;
  const int b = blockIdx.x >> 2;
  const int t0 = (blockIdx.x & 3) << 7;

  f32x4 acc[4][4];
#pragma unroll
  for (int m = 0; m < 4; ++m)
#pragma unroll
    for (int n = 0; n < 4; ++n) acc[m][n] = (f32x4)(0.f);

  const int ar = tid >> 1;
  const int ae = (tid & 1) << 5;
  const int swz = (ar & 7) << 4;

  float2 av[16];
  uint4 bv[4];

  int k = 0, f0 = 0;
  {
    const int trow = t0 + ar + k - 1;
    const bool rowok = (trow >= 0) && (trow < T_);
    const float* srcrow = x + ((long)b * T_ + (rowok ? trow : 0)) * F_;
#pragma unroll
    for (int j = 0; j < 16; ++j) {
      const int f = f0 + ae + 2 * j;
      float2 v = {0.f, 0.f};
      if (rowok && f < F_) v = *(const float2*)(srcrow + f);
      av[j] = v;
    }
    const ushort* srcb = wbT + ar * KPAD + 0 * 64 + ae;
#pragma unroll
    for (int j = 0; j < 4; ++j) bv[j] = *(const uint4*)(srcb + 8 * j);
  }

  for (int ks = 0; ks < NKS; ++ks) {
    __syncthreads();
    {
      char* arow = (char*)As + ar * 128;
      char* brow = (char*)Bs + ar * 128;
#pragma unroll
      for (int j16 = 0; j16 < 4; ++j16) {
        uint4 p;
        p.x = packbf2(av[4 * j16 + 0].x, av[4 * j16 + 0].y);
        p.y = packbf2(av[4 * j16 + 1].x, av[4 * j16 + 1].y);
        p.z = packbf2(av[4 * j16 + 2].x, av[4 * j16 + 2].y);
        p.w = packbf2(av[4 * j16 + 3].x, av[4 * j16 + 3].y);
        const int inner = ((ae << 1) + (j16 << 4)) ^ swz;
        *(uint4*)(arow + inner) = p;
        *(uint4*)(brow + inner) = bv[j16];
      }
    }
    __syncthreads();

    if (ks + 1 < NKS) {
      f0 += 64;
      if (f0 == 384) { f0 = 0; ++k; }
      const int trow = t0 + ar + k - 1;
      const bool rowok = (trow >= 0) && (trow < T_);
      const float* srcrow = x + ((long)b * T_ + (rowok ? trow : 0)) * F_;
#pragma unroll
      for (int j = 0; j < 16; ++j) {
        const int f = f0 + ae + 2 * j;
        float2 v = {0.f, 0.f};
        if (rowok && f < F_) v = *(const float2*)(srcrow + f);
        av[j] = v;
      }
      const ushort* srcb = wbT + ar * KPAD + (ks + 1) * 64 + ae;
#pragma unroll
      for (int j = 0; j < 4; ++j) bv[j] = *(const uint4*)(srcb + 8 * j);
    }

#pragma unroll
    for (int s = 0; s < 2; ++s) {
      bf16x8 af[4], bf[4];
      const int ksub = s * 64 + ((lane >> 4) << 4);
      const int rsw = (lane & 7) << 4;
#pragma unroll
      for (int m = 0; m < 4; ++m) {
        const int r = wr * 64 + m * 16 + (lane & 15);
        af[m] = *(const bf16x8*)((const char*)As + r * 128 + (ksub ^ rsw));
      }
#pragma unroll
      for (int n = 0; n < 4; ++n) {
        const int r = wc * 64 + n * 16 + (lane & 15);
        bf[n] = *(const bf16x8*)((const char*)Bs + r * 128 + (ksub ^ rsw));
      }
#pragma unroll
      for (int m = 0; m < 4; ++m)
#pragma unroll
        for (int n = 0; n < 4; ++n)
          acc[m][n] =
              __builtin_amdgcn_mfma_f32_16x16x32_bf16(af[m], bf[n], acc[m][n], 0, 0, 0);
    }
  }

  float bc[4];
#pragma unroll
  for (int n = 0; n < 4; ++n) bc[n] = bias[wc * 64 + n * 16 + (lane & 15)];
#pragma unroll
  for (int m = 0; m < 4; ++m) {
    const int trowbase = t0 + wr * 64 + m * 16 + ((lane >> 4) << 2);
#pragma unroll
    for (int n = 0; n < 4; ++n) {
      const int c = wc * 64 + n * 16 + (lane & 15);
#pragma unroll
      for (int r = 0; r < 4; ++r) {
        float v = acc[m][n][r] + bc[n];
        v = v > 0.f ? v : 0.f;
        y[((long)b * T_ + trowbase + r) * C_ + c] = f2bf(v);
      }
    }
  }
}

// ---------------- Fused BiLSTM: per-chunk MFMA input-proj + scalar scan ----
// One block per (b,dir), 256 threads. 16 chunks x 32 steps.
// Per chunk: stage y[32x128] bf16 in LDS (swizzled) -> xg = y @ w_ih^T via
// MFMA (w_ih B-frags pinned in VGPRs) -> xgL[32x256] fp32 in LDS -> 32
// recurrence steps (thread g = gate g; 64-wide dot, 4 split accumulators).
__device__ __forceinline__ float sigm(float v) {
  return 1.f / (1.f + __expf(-v));
}
__device__ __forceinline__ float tanh_fast(float v) {
  return 2.f / (1.f + __expf(-2.f * v)) - 1.f;
}

__global__ __launch_bounds__(256, 2) void lstm_kernel(
    const ushort* __restrict__ y, const ushort* __restrict__ wbI,
    const float* __restrict__ w_hh_f, const float* __restrict__ b_f,
    const float* __restrict__ w_hh_b, const float* __restrict__ b_b,
    float* __restrict__ out) {
  const int dir = blockIdx.x & 1;
  const int b = blockIdx.x >> 1;
  const int g = threadIdx.x;
  const int lane = g & 63;
  const int wid = g >> 6;

  const float* whh = dir ? w_hh_b : w_hh_f;
  const float* bbp = dir ? b_b : b_f;

  // w_hh row for gate g (fp32, 64) in regs
  f32x4 wv[16];
  {
    const f32x4* wr4 = (const f32x4*)(whh + g * 64);
#pragma unroll
    for (int i = 0; i < 16; ++i) wv[i] = wr4[i];
  }
  const float bg = bbp[g];

  // w_ih B-frags for this wave's 64 gate rows (bf16, pinned: 64 VGPRs)
  bf16x8 bfrag[4][4];
  {
    const ushort* wb0 = wbI + dir * 32768;
#pragma unroll
    for (int n = 0; n < 4; ++n) {
      const int row = wid * 64 + n * 16 + (lane & 15);
#pragma unroll
      for (int ks = 0; ks < 4; ++ks)
        bfrag[n][ks] =
            *(const bf16x8*)(wb0 + row * 128 + ks * 32 + ((lane >> 4) << 3));
    }
  }

  __shared__ __align__(16) ushort ys[32 * 128];  // 8KB, swizzled 256B rows
  __shared__ __align__(16) float xgL[32 * 256];  // 32KB
  __shared__ __align__(16) float hs[64];
  __shared__ float gates[256];

  float cst = 0.f;
  if (g < 64) hs[g] = 0.f;

  const int sr = g >> 3;        // staging row 0..31
  const int sj = (g & 7) * 32;  // inner byte base
  const int ssw = (sr & 7) << 4;

  for (int cc = 0; cc < 16; ++cc) {
    const int cb = dir ? (T_ - 32 * (cc + 1)) : 32 * cc;

    // ---- stage y chunk -> ys (inverse-swizzled source, swizzled reads) ----
    {
      const ushort* srow = y + ((long)b * T_ + cb + sr) * 128;
      uint4 v0 = *(const uint4*)(srow + ((sj ^ ssw) >> 1));
      uint4 v1 = *(const uint4*)(srow + ((((sj + 16)) ^ ssw) >> 1));
      *(uint4*)((char*)ys + sr * 256 + sj) = v0;
      *(uint4*)((char*)ys + sr * 256 + sj + 16) = v1;
    }
    __syncthreads();

    // ---- xg chunk GEMM: [32 t x 256 g] = ys @ w_ih^T ----
    f32x4 acc[2][4];
#pragma unroll
    for (int m = 0; m < 2; ++m)
#pragma unroll
      for (int n = 0; n < 4; ++n) acc[m][n] = (f32x4)(0.f);
#pragma unroll
    for (int ks = 0; ks < 4; ++ks) {
      const int ksub = ks * 64 + ((lane >> 4) << 4);
      bf16x8 af[2];
#pragma unroll
      for (int m = 0; m < 2; ++m) {
        const int r = m * 16 + (lane & 15);
        af[m] = *(const bf16x8*)((const char*)ys + r * 256 +
                                 (ksub ^ ((r & 7) << 4)));
      }
#pragma unroll
      for (int n = 0; n < 4; ++n) {
        acc[0][n] = __builtin_amdgcn_mfma_f32_16x16x32_bf16(af[0], bfrag[n][ks],
                                                            acc[0][n], 0, 0, 0);
        acc[1][n] = __builtin_amdgcn_mfma_f32_16x16x32_bf16(af[1], bfrag[n][ks],
                                                            acc[1][n], 0, 0, 0);
      }
    }
#pragma unroll
    for (int m = 0; m < 2; ++m)
#pragma unroll
      for (int n = 0; n < 4; ++n) {
        const int col = wid * 64 + n * 16 + (lane & 15);
#pragma unroll
        for (int r = 0; r < 4; ++r) {
          const int tl = m * 16 + ((lane >> 4) << 2) + r;
          xgL[tl * 256 + col] = acc[m][n][r];
        }
      }
    __syncthreads();

    // ---- 32 recurrence steps ----
    for (int sl = 0; sl < 32; ++sl) {
      const int tl = dir ? (31 - sl) : sl;
      const f32x4* h4 = (const f32x4*)hs;
      float a0 = 0.f, a1 = 0.f, a2 = 0.f, a3 = 0.f;
#pragma unroll
      for (int q = 0; q < 4; ++q) {
        f32x4 h0 = h4[q * 4 + 0], h1 = h4[q * 4 + 1];
        f32x4 h2 = h4[q * 4 + 2], h3 = h4[q * 4 + 3];
        f32x4 w0 = wv[q * 4 + 0], w1 = wv[q * 4 + 1];
        f32x4 w2 = wv[q * 4 + 2], w3 = wv[q * 4 + 3];
        a0 += h0.x * w0.x + h0.y * w0.y + h0.z * w0.z + h0.w * w0.w;
        a1 += h1.x * w1.x + h1.y * w1.y + h1.z * w1.z + h1.w * w1.w;
        a2 += h2.x * w2.x + h2.y * w2.y + h2.z * w2.z + h2.w * w2.w;
        a3 += h3.x * w3.x + h3.y * w3.y + h3.z * w3.z + h3.w * w3.w;
      }
      gates[g] = ((a0 + a1) + (a2 + a3)) + xgL[tl * 256 + g] + bg;
      __syncthreads();
      if (g < 64) {
        float gi = gates[g], gf = gates[64 + g];
        float gc = gates[128 + g], go = gates[192 + g];
        cst = sigm(gf) * cst + sigm(gi) * tanh_fast(gc);
        float h = sigm(go) * tanh_fast(cst);
        hs[g] = h;
        out[((long)b * T_ + cb + tl) * (2 * H_) + dir * H_ + g] = h;
      }
      __syncthreads();
    }
  }
}

// ---------------- Attention pool + LayerNorm + FC ----------------
__global__ __launch_bounds__(256) void head_kernel(
    const float* __restrict__ hio, const float* __restrict__ attn_w,
    const float* __restrict__ attn_b, const float* __restrict__ ln_g,
    const float* __restrict__ ln_b, const float* __restrict__ fc_w,
    const float* __restrict__ fc_b, float* __restrict__ res) {
  const int b = blockIdx.x;
  const int tid = threadIdx.x;
  __shared__ __align__(16) float aw[128];
  __shared__ float l[T_];
  __shared__ float red[16];
  __shared__ float pp[2][128];
  __shared__ float normed[128];
  if (tid < 128) aw[tid] = attn_w[tid];
  __syncthreads();
  const float ab = attn_b[0];

  for (int t = tid; t < T_; t += 256) {
    const float* row = hio + ((long)b * T_ + t) * 128;
    float a = ab;
#pragma unroll
    for (int d = 0; d < 128; d += 4) {
      float4 r4 = *(const float4*)&row[d];
      float4 w4 = *(const float4*)&aw[d];
      a += r4.x * w4.x + r4.y * w4.y + r4.z * w4.z + r4.w * w4.w;
    }
    l[t] = a;
  }
  __syncthreads();

  float v0 = l[tid], v1 = l[tid + 256];
  float m = fmaxf(v0, v1);
#pragma unroll
  for (int off = 32; off >= 1; off >>= 1) m = fmaxf(m, __shfl_xor(m, off));
  if ((tid & 63) == 0) red[tid >> 6] = m;
  __syncthreads();
  m = fmaxf(fmaxf(red[0], red[1]), fmaxf(red[2], red[3]));
  float e0 = __expf(v0 - m), e1 = __expf(v1 - m);
  float ssum = e0 + e1;
#pragma unroll
  for (int off = 32; off >= 1; off >>= 1) ssum += __shfl_xor(ssum, off);
  if ((tid & 63) == 0) red[4 + (tid >> 6)] = ssum;
  __syncthreads();
  float inv = 1.f / (red[4] + red[5] + red[6] + red[7]);
  l[tid] = e0 * inv;
  l[tid + 256] = e1 * inv;
  __syncthreads();

  const int d = tid & 127, half = tid >> 7;
  float p = 0.f;
  for (int t = half * 256; t < half * 256 + 256; ++t)
    p += l[t] * hio[((long)b * T_ + t) * 128 + d];
  pp[half][d] = p;
  __syncthreads();

  if (tid < 128) {
    float pv = pp[0][tid] + pp[1][tid];
    float s1 = pv, s2 = pv * pv;
#pragma unroll
    for (int off = 32; off >= 1; off >>= 1) {
      s1 += __shfl_xor(s1, off);
      s2 += __shfl_xor(s2, off);
    }
    if ((tid & 63) == 0) {
      red[8 + (tid >> 6) * 2] = s1;
      red[9 + (tid >> 6) * 2] = s2;
    }
  }
  __syncthreads();
  if (tid < 128) {
    float s1 = red[8] + red[10], s2 = red[9] + red[11];
    float mu = s1 * (1.f / 128.f);
    float var = s2 * (1.f / 128.f) - mu * mu;
    float rinv = rsqrtf(var + 1e-5f);
    float pv = pp[0][tid] + pp[1][tid];
    normed[tid] = (pv - mu) * rinv * ln_g[tid] + ln_b[tid];
  }
  __syncthreads();

  if (tid < 2) {
    float a = fc_b[tid];
    for (int d2 = 0; d2 < 128; ++d2) a += normed[d2] * fc_w[tid * 128 + d2];
    res[b * 2 + tid] = a;
  }
}

extern "C" void kernel_launch(void* const* d_in, const int* in_sizes, int n_in,
                              void* d_out, int out_size, void* d_ws,
                              size_t ws_size, hipStream_t stream) {
  const float* x = (const float*)d_in[0];
  const float* conv_w = (const float*)d_in[1];
  const float* conv_b = (const float*)d_in[2];
  const float* w_ih_f = (const float*)d_in[3];
  const float* w_hh_f = (const float*)d_in[4];
  const float* b_f = (const float*)d_in[5];
  const float* w_ih_b = (const float*)d_in[6];
  const float* w_hh_b = (const float*)d_in[7];
  const float* b_b = (const float*)d_in[8];
  const float* attn_w = (const float*)d_in[9];
  const float* attn_b = (const float*)d_in[10];
  const float* ln_g = (const float*)d_in[11];
  const float* ln_b = (const float*)d_in[12];
  const float* fc_w = (const float*)d_in[13];
  const float* fc_b = (const float*)d_in[14];
  float* res = (float*)d_out;

  // ws layout (~102 MiB):
  ushort* wbT = (ushort*)d_ws;                               // 294,912 B
  ushort* wbI = (ushort*)((char*)d_ws + 524288);             // 131,072 B
  ushort* y = (ushort*)((char*)d_ws + 1048576);              // 33,554,432 B
  float* hout = (float*)((char*)d_ws + 1048576 + 33554432);  // 67,108,864 B

  pack_w_kernel<<<(C_ * KPAD + 255) / 256, 256, 0, stream>>>(conv_w, wbT);
  pack_wi_kernel<<<256, 256, 0, stream>>>(w_ih_f, w_ih_b, wbI);
  conv_gemm_kernel<<<B_ * (T_ / 128), 256, 0, stream>>>(x, wbT, conv_b, y);
  lstm_kernel<<<B_ * 2, 256, 0, stream>>>(y, wbI, w_hh_f, b_f, w_hh_b, b_b,
                                          hout);
  head_kernel<<<B_, 256, 0, stream>>>(hout, attn_w, attn_b, ln_g, ln_b, fc_w,
                                      fc_b, res);
}

// Round 4
// 549.218 us; speedup vs baseline: 5.0287x; 1.6383x over previous
//
#include <hip/hip_runtime.h>
#include <math.h>

typedef unsigned int uint;
typedef unsigned short ushort;

#define B_ 256
#define T_ 512
#define F_ 378
#define C_ 128
#define H_ 64
#define KPAD 1152   // 3 * 384

using f32x4 = __attribute__((ext_vector_type(4))) float;
using bf16x8 = __attribute__((ext_vector_type(8))) short;

__device__ __forceinline__ ushort f2bf(float f) {
  union { float f; uint u; } c; c.f = f;
  uint r = (c.u + 0x7fffu + ((c.u >> 16) & 1u)) >> 16;
  return (ushort)r;
}
__device__ __forceinline__ float bf2f(ushort u) {
  union { uint u; float f; } c; c.u = ((uint)u) << 16;
  return c.f;
}
__device__ __forceinline__ uint packbf2(float a, float b) {
  return (uint)f2bf(a) | (((uint)f2bf(b)) << 16);
}

// ---------------- pack w -> wbT[c][kk], kk = k*384 + f, bf16, zero-padded ---
__global__ __launch_bounds__(256) void pack_w_kernel(
    const float* __restrict__ w, ushort* __restrict__ wbT) {
  int i = blockIdx.x * 256 + threadIdx.x;
  if (i >= C_ * KPAD) return;
  int c = i / KPAD, kk = i - c * KPAD;
  int k = kk / 384, f = kk - k * 384;
  float v = (f < F_) ? w[c * (F_ * 3) + f * 3 + k] : 0.f;
  wbT[i] = f2bf(v);
}

// ---------------- pack w_ih (both dirs) -> wbI[dir][g][c] bf16 -------------
__global__ __launch_bounds__(256) void pack_wi_kernel(
    const float* __restrict__ wf, const float* __restrict__ wb,
    ushort* __restrict__ wbI) {
  int i = blockIdx.x * 256 + threadIdx.x;  // 2*256*128 = 65536
  int dir = i >> 15, rem = i & 32767;
  const float* src = dir ? wb : wf;
  wbI[i] = f2bf(src[rem]);
}

// ---------------- Conv1d as implicit GEMM, bf16 MFMA, k-reuse version ------
// Per block: 128 t-rows x 128 c. 6 f-slices of 64; x rows t0-1..t0+128 staged
// ONCE per slice (bf16, swizzled), reused for all 3 kernel taps (A-frag row =
// m_row + k). B (wbT, L2-resident) staged per slice for all 3 k. Epilogue:
// LDS transpose (reusing Bs) -> fully coalesced 1KB/wave dwordx4 stores.
__global__ __launch_bounds__(256, 2) void conv_gemm_kernel(
    const float* __restrict__ x, const ushort* __restrict__ wbT,
    const float* __restrict__ bias, ushort* __restrict__ y) {
  __shared__ __align__(16) char xsb[130 * 128];  // 16.25 KB
  __shared__ __align__(16) char bsb[128 * 384];  // 48 KB (also epilogue trans)
  const int tid = threadIdx.x;
  const int lane = tid & 63;
  const int wr = (tid >> 7) & 1;
  const int wc = (tid >> 6) & 1;
  const int b = blockIdx.x >> 2;
  const int t0 = (blockIdx.x & 3) << 7;

  f32x4 acc[4][4];
#pragma unroll
  for (int m = 0; m < 4; ++m)
#pragma unroll
    for (int n = 0; n < 4; ++n) acc[m][n] = (f32x4)(0.f);

  for (int fs = 0; fs < 6; ++fs) {
    __syncthreads();  // previous slice's readers done

    // ---- stage A: task (r,h) = 32 floats x[b][t0-1+r][fs*64+h*32..] ----
    {
      auto stage_a = [&](int r, int h) {
        const int t = t0 - 1 + r;
        const bool ok = (t >= 0) && (t < T_);
        const float* srow = x + ((long)b * T_ + (ok ? t : 0)) * F_;
        const int fb = fs * 64 + h * 32;
        char* dst = xsb + r * 128;
        const int sw = (r & 7) << 4;
        uint pk[16];
        if (ok && fb + 31 < F_) {
#pragma unroll
          for (int j = 0; j < 16; ++j) {
            float2 v = *(const float2*)(srow + fb + 2 * j);  // 8B-aligned
            pk[j] = packbf2(v.x, v.y);
          }
        } else {
#pragma unroll
          for (int j = 0; j < 16; ++j) {
            const int f = fb + 2 * j;
            float a = (ok && f < F_) ? srow[f] : 0.f;
            float c2 = (ok && f + 1 < F_) ? srow[f + 1] : 0.f;
            pk[j] = packbf2(a, c2);
          }
        }
#pragma unroll
        for (int j = 0; j < 4; ++j) {
          uint4 p = {pk[4 * j], pk[4 * j + 1], pk[4 * j + 2], pk[4 * j + 3]};
          *(uint4*)(dst + ((h * 64 + j * 16) ^ sw)) = p;
        }
      };
      stage_a(tid >> 1, tid & 1);
      if (tid < 4) stage_a(128 + (tid >> 1), tid & 1);
    }

    // ---- stage B: c = tid>>1, h = tid&1; 3 k x 64B each ----
    {
      const int c = tid >> 1, h = tid & 1;
      const ushort* src = wbT + c * KPAD + fs * 64 + h * 32;
      char* drow = bsb + c * 384;
      const int sw = (c & 7) << 4;
#pragma unroll
      for (int k = 0; k < 3; ++k)
#pragma unroll
        for (int j = 0; j < 4; ++j) {
          uint4 v = *(const uint4*)(src + k * 384 + j * 8);
          *(uint4*)(drow + k * 128 + ((h * 64 + j * 16) ^ sw)) = v;
        }
    }
    __syncthreads();

    // ---- MFMA: 3 taps x 2 k-slices x 16 = 96 MFMA / wave / slice ----
#pragma unroll
    for (int k = 0; k < 3; ++k) {
#pragma unroll
      for (int s = 0; s < 2; ++s) {
        bf16x8 af[4], bfx[4];
        const int ksub = s * 64 + ((lane >> 4) << 4);
#pragma unroll
        for (int m = 0; m < 4; ++m) {
          const int rr = wr * 64 + m * 16 + (lane & 15) + k;
          af[m] = *(const bf16x8*)(xsb + rr * 128 + (ksub ^ ((rr & 7) << 4)));
        }
#pragma unroll
        for (int n = 0; n < 4; ++n) {
          const int c = wc * 64 + n * 16 + (lane & 15);
          bfx[n] =
              *(const bf16x8*)(bsb + c * 384 + k * 128 + (ksub ^ ((c & 7) << 4)));
        }
#pragma unroll
        for (int m = 0; m < 4; ++m)
#pragma unroll
          for (int n = 0; n < 4; ++n)
            acc[m][n] = __builtin_amdgcn_mfma_f32_16x16x32_bf16(
                af[m], bfx[n], acc[m][n], 0, 0, 0);
      }
    }
  }

  // ---- epilogue: bias+ReLU -> LDS transpose (in bsb) -> coalesced stores ---
  __syncthreads();  // done reading bsb as B
  float bc[4];
#pragma unroll
  for (int n = 0; n < 4; ++n) bc[n] = bias[wc * 64 + n * 16 + (lane & 15)];
#pragma unroll
  for (int m = 0; m < 4; ++m) {
#pragma unroll
    for (int n = 0; n < 4; ++n) {
      const int col = wc * 64 + n * 16 + (lane & 15);
#pragma unroll
      for (int r = 0; r < 4; ++r) {
        const int row = wr * 64 + m * 16 + ((lane >> 4) << 2) + r;
        float v = acc[m][n][r] + bc[n];
        v = v > 0.f ? v : 0.f;
        *(ushort*)(bsb + row * 256 + ((col * 2) ^ ((row & 7) << 4))) = f2bf(v);
      }
    }
  }
  __syncthreads();
  const int w = tid >> 6;
#pragma unroll
  for (int p = 0; p < 8; ++p) {
    const int rowb = p * 16 + w * 4 + (lane >> 4);
    const int colb = (lane & 15) * 16;  // byte offset within 256B row
    uint4 v = *(const uint4*)(bsb + rowb * 256 + (colb ^ ((rowb & 7) << 4)));
    *(uint4*)((char*)(y + ((long)b * T_ + t0 + rowb) * 128) + colb) = v;
  }
}

// ---------------- Fused BiLSTM: per-chunk MFMA input-proj + scalar scan ----
__device__ __forceinline__ float sigm(float v) {
  return 1.f / (1.f + __expf(-v));
}
__device__ __forceinline__ float tanh_fast(float v) {
  return 2.f / (1.f + __expf(-2.f * v)) - 1.f;
}

__global__ __launch_bounds__(256, 2) void lstm_kernel(
    const ushort* __restrict__ y, const ushort* __restrict__ wbI,
    const float* __restrict__ w_hh_f, const float* __restrict__ b_f,
    const float* __restrict__ w_hh_b, const float* __restrict__ b_b,
    float* __restrict__ out) {
  const int dir = blockIdx.x & 1;
  const int b = blockIdx.x >> 1;
  const int g = threadIdx.x;
  const int lane = g & 63;
  const int wid = g >> 6;

  const float* whh = dir ? w_hh_b : w_hh_f;
  const float* bbp = dir ? b_b : b_f;

  f32x4 wv[16];
  {
    const f32x4* wr4 = (const f32x4*)(whh + g * 64);
#pragma unroll
    for (int i = 0; i < 16; ++i) wv[i] = wr4[i];
  }
  const float bg = bbp[g];

  bf16x8 bfrag[4][4];
  {
    const ushort* wb0 = wbI + dir * 32768;
#pragma unroll
    for (int n = 0; n < 4; ++n) {
      const int row = wid * 64 + n * 16 + (lane & 15);
#pragma unroll
      for (int ks = 0; ks < 4; ++ks)
        bfrag[n][ks] =
            *(const bf16x8*)(wb0 + row * 128 + ks * 32 + ((lane >> 4) << 3));
    }
  }

  __shared__ __align__(16) ushort ys[32 * 128];
  __shared__ __align__(16) float xgL[32 * 256];
  __shared__ __align__(16) float hs[64];
  __shared__ float gates[256];

  float cst = 0.f;
  if (g < 64) hs[g] = 0.f;

  const int sr = g >> 3;
  const int sj = (g & 7) * 32;
  const int ssw = (sr & 7) << 4;

  for (int cc = 0; cc < 16; ++cc) {
    const int cb = dir ? (T_ - 32 * (cc + 1)) : 32 * cc;

    {
      const ushort* srow = y + ((long)b * T_ + cb + sr) * 128;
      uint4 v0 = *(const uint4*)(srow + ((sj ^ ssw) >> 1));
      uint4 v1 = *(const uint4*)(srow + ((((sj + 16)) ^ ssw) >> 1));
      *(uint4*)((char*)ys + sr * 256 + sj) = v0;
      *(uint4*)((char*)ys + sr * 256 + sj + 16) = v1;
    }
    __syncthreads();

    f32x4 acc[2][4];
#pragma unroll
    for (int m = 0; m < 2; ++m)
#pragma unroll
      for (int n = 0; n < 4; ++n) acc[m][n] = (f32x4)(0.f);
#pragma unroll
    for (int ks = 0; ks < 4; ++ks) {
      const int ksub = ks * 64 + ((lane >> 4) << 4);
      bf16x8 af[2];
#pragma unroll
      for (int m = 0; m < 2; ++m) {
        const int r = m * 16 + (lane & 15);
        af[m] = *(const bf16x8*)((const char*)ys + r * 256 +
                                 (ksub ^ ((r & 7) << 4)));
      }
#pragma unroll
      for (int n = 0; n < 4; ++n) {
        acc[0][n] = __builtin_amdgcn_mfma_f32_16x16x32_bf16(af[0], bfrag[n][ks],
                                                            acc[0][n], 0, 0, 0);
        acc[1][n] = __builtin_amdgcn_mfma_f32_16x16x32_bf16(af[1], bfrag[n][ks],
                                                            acc[1][n], 0, 0, 0);
      }
    }
#pragma unroll
    for (int m = 0; m < 2; ++m)
#pragma unroll
      for (int n = 0; n < 4; ++n) {
        const int col = wid * 64 + n * 16 + (lane & 15);
#pragma unroll
        for (int r = 0; r < 4; ++r) {
          const int tl = m * 16 + ((lane >> 4) << 2) + r;
          xgL[tl * 256 + col] = acc[m][n][r];
        }
      }
    __syncthreads();

    for (int sl = 0; sl < 32; ++sl) {
      const int tl = dir ? (31 - sl) : sl;
      const f32x4* h4 = (const f32x4*)hs;
      float a0 = 0.f, a1 = 0.f, a2 = 0.f, a3 = 0.f;
#pragma unroll
      for (int q = 0; q < 4; ++q) {
        f32x4 h0 = h4[q * 4 + 0], h1 = h4[q * 4 + 1];
        f32x4 h2 = h4[q * 4 + 2], h3 = h4[q * 4 + 3];
        f32x4 w0 = wv[q * 4 + 0], w1 = wv[q * 4 + 1];
        f32x4 w2 = wv[q * 4 + 2], w3 = wv[q * 4 + 3];
        a0 += h0.x * w0.x + h0.y * w0.y + h0.z * w0.z + h0.w * w0.w;
        a1 += h1.x * w1.x + h1.y * w1.y + h1.z * w1.z + h1.w * w1.w;
        a2 += h2.x * w2.x + h2.y * w2.y + h2.z * w2.z + h2.w * w2.w;
        a3 += h3.x * w3.x + h3.y * w3.y + h3.z * w3.z + h3.w * w3.w;
      }
      gates[g] = ((a0 + a1) + (a2 + a3)) + xgL[tl * 256 + g] + bg;
      __syncthreads();
      if (g < 64) {
        float gi = gates[g], gf = gates[64 + g];
        float gc = gates[128 + g], go = gates[192 + g];
        cst = sigm(gf) * cst + sigm(gi) * tanh_fast(gc);
        float h = sigm(go) * tanh_fast(cst);
        hs[g] = h;
        out[((long)b * T_ + cb + tl) * (2 * H_) + dir * H_ + g] = h;
      }
      __syncthreads();
    }
  }
}

// ---------------- Attention pool + LayerNorm + FC ----------------
__global__ __launch_bounds__(256) void head_kernel(
    const float* __restrict__ hio, const float* __restrict__ attn_w,
    const float* __restrict__ attn_b, const float* __restrict__ ln_g,
    const float* __restrict__ ln_b, const float* __restrict__ fc_w,
    const float* __restrict__ fc_b, float* __restrict__ res) {
  const int b = blockIdx.x;
  const int tid = threadIdx.x;
  __shared__ __align__(16) float aw[128];
  __shared__ float l[T_];
  __shared__ float red[16];
  __shared__ float pp[2][128];
  __shared__ float normed[128];
  if (tid < 128) aw[tid] = attn_w[tid];
  __syncthreads();
  const float ab = attn_b[0];

  for (int t = tid; t < T_; t += 256) {
    const float* row = hio + ((long)b * T_ + t) * 128;
    float a = ab;
#pragma unroll
    for (int d = 0; d < 128; d += 4) {
      float4 r4 = *(const float4*)&row[d];
      float4 w4 = *(const float4*)&aw[d];
      a += r4.x * w4.x + r4.y * w4.y + r4.z * w4.z + r4.w * w4.w;
    }
    l[t] = a;
  }
  __syncthreads();

  float v0 = l[tid], v1 = l[tid + 256];
  float m = fmaxf(v0, v1);
#pragma unroll
  for (int off = 32; off >= 1; off >>= 1) m = fmaxf(m, __shfl_xor(m, off));
  if ((tid & 63) == 0) red[tid >> 6] = m;
  __syncthreads();
  m = fmaxf(fmaxf(red[0], red[1]), fmaxf(red[2], red[3]));
  float e0 = __expf(v0 - m), e1 = __expf(v1 - m);
  float ssum = e0 + e1;
#pragma unroll
  for (int off = 32; off >= 1; off >>= 1) ssum += __shfl_xor(ssum, off);
  if ((tid & 63) == 0) red[4 + (tid >> 6)] = ssum;
  __syncthreads();
  float inv = 1.f / (red[4] + red[5] + red[6] + red[7]);
  l[tid] = e0 * inv;
  l[tid + 256] = e1 * inv;
  __syncthreads();

  const int d = tid & 127, half = tid >> 7;
  float p = 0.f;
  for (int t = half * 256; t < half * 256 + 256; ++t)
    p += l[t] * hio[((long)b * T_ + t) * 128 + d];
  pp[half][d] = p;
  __syncthreads();

  if (tid < 128) {
    float pv = pp[0][tid] + pp[1][tid];
    float s1 = pv, s2 = pv * pv;
#pragma unroll
    for (int off = 32; off >= 1; off >>= 1) {
      s1 += __shfl_xor(s1, off);
      s2 += __shfl_xor(s2, off);
    }
    if ((tid & 63) == 0) {
      red[8 + (tid >> 6) * 2] = s1;
      red[9 + (tid >> 6) * 2] = s2;
    }
  }
  __syncthreads();
  if (tid < 128) {
    float s1 = red[8] + red[10], s2 = red[9] + red[11];
    float mu = s1 * (1.f / 128.f);
    float var = s2 * (1.f / 128.f) - mu * mu;
    float rinv = rsqrtf(var + 1e-5f);
    float pv = pp[0][tid] + pp[1][tid];
    normed[tid] = (pv - mu) * rinv * ln_g[tid] + ln_b[tid];
  }
  __syncthreads();

  if (tid < 2) {
    float a = fc_b[tid];
    for (int d2 = 0; d2 < 128; ++d2) a += normed[d2] * fc_w[tid * 128 + d2];
    res[b * 2 + tid] = a;
  }
}

extern "C" void kernel_launch(void* const* d_in, const int* in_sizes, int n_in,
                              void* d_out, int out_size, void* d_ws,
                              size_t ws_size, hipStream_t stream) {
  const float* x = (const float*)d_in[0];
  const float* conv_w = (const float*)d_in[1];
  const float* conv_b = (const float*)d_in[2];
  const float* w_ih_f = (const float*)d_in[3];
  const float* w_hh_f = (const float*)d_in[4];
  const float* b_f = (const float*)d_in[5];
  const float* w_ih_b = (const float*)d_in[6];
  const float* w_hh_b = (const float*)d_in[7];
  const float* b_b = (const float*)d_in[8];
  const float* attn_w = (const float*)d_in[9];
  const float* attn_b = (const float*)d_in[10];
  const float* ln_g = (const float*)d_in[11];
  const float* ln_b = (const float*)d_in[12];
  const float* fc_w = (const float*)d_in[13];
  const float* fc_b = (const float*)d_in[14];
  float* res = (float*)d_out;

  // ws layout (~102 MiB):
  ushort* wbT = (ushort*)d_ws;                               // 294,912 B
  ushort* wbI = (ushort*)((char*)d_ws + 524288);             // 131,072 B
  ushort* y = (ushort*)((char*)d_ws + 1048576);              // 33,554,432 B
  float* hout = (float*)((char*)d_ws + 1048576 + 33554432);  // 67,108,864 B

  pack_w_kernel<<<(C_ * KPAD + 255) / 256, 256, 0, stream>>>(conv_w, wbT);
  pack_wi_kernel<<<256, 256, 0, stream>>>(w_ih_f, w_ih_b, wbI);
  conv_gemm_kernel<<<B_ * (T_ / 128), 256, 0, stream>>>(x, wbT, conv_b, y);
  lstm_kernel<<<B_ * 2, 256, 0, stream>>>(y, wbI, w_hh_f, b_f, w_hh_b, b_b,
                                          hout);
  head_kernel<<<B_, 256, 0, stream>>>(hout, attn_w, attn_b, ln_g, ln_b, fc_w,
                                      fc_b, res);
}